// Round 5
// baseline (550.514 us; speedup 1.0000x reference)
//
#include <hip/hip_runtime.h>
#include <stdint.h>

// RandomSegmentMask: B=64, S=128, T=4096
// mask[b,s,t] = exists start in [t - m_s, t];  out = mask ? mask_value : x
// One block per (b,s) row: per-thread local cumsum (16 elems), wave shuffle
// scan + cross-wave combine, full cs row staged in LDS (XOR-swizzled),
// windowed difference, vectorized float4 writeback of out and mask.
//
// R4 fix: idx_mask is delivered as int32 (numpy bool -> "integer -> const int*"
// per harness contract), NOT 1-byte bool. R4's uint8 read scrambled the mask
// (absmax 5.125 = max|x| at mask disagreements).

#define TDIM 4096
#define SDIM 128
#define THREADS 256
#define PER_THREAD (TDIM / THREADS) // 16
#define WAVES (THREADS / 64)        // 4

// word-index swizzle: XOR low-5 bits with bits 5..9. Bijective (involution)
// within a 4096-word row. Turns the stride-16 (32-way) pattern into <=2-way.
__device__ __forceinline__ int swz(int a) { return a ^ ((a >> 5) & 31); }

__global__ __launch_bounds__(THREADS)
void segmask_kernel(const float* __restrict__ x,
                    const int* __restrict__ idx_mask,
                    const int* __restrict__ mask_size,
                    const int* __restrict__ mask_value_p,
                    float* __restrict__ out,
                    float* __restrict__ mask_out,
                    int write_mask)
{
    __shared__ int cs[TDIM];        // 16 KB, swizzled word index
    __shared__ int wsum[WAVES];     // per-wave totals

    const int row  = blockIdx.x;                // b*S + s
    const int s    = row & (SDIM - 1);
    const int tid  = threadIdx.x;
    const int lane = tid & 63;
    const int wv   = tid >> 6;
    const long long base = (long long)row * TDIM;

    // ---- load 16 int32 bools (4 x 16B, per-thread contiguous) ----
    const int4* im4 = reinterpret_cast<const int4*>(idx_mask + base);
    int loc[PER_THREAD];
    int run = 0;
    #pragma unroll
    for (int j = 0; j < 4; ++j) {
        int4 v = im4[tid * 4 + j];
        run += (v.x != 0); loc[j * 4 + 0] = run;
        run += (v.y != 0); loc[j * 4 + 1] = run;
        run += (v.z != 0); loc[j * 4 + 2] = run;
        run += (v.w != 0); loc[j * 4 + 3] = run;
    }

    // ---- wave-level inclusive scan of per-thread sums (64 lanes) ----
    int ws = run;
    #pragma unroll
    for (int off = 1; off < 64; off <<= 1) {
        int up = __shfl_up(ws, off, 64);
        if (lane >= off) ws += up;
    }
    if (lane == 63) wsum[wv] = ws;     // wave total
    __syncthreads();

    // exclusive prefix of wave totals (4 waves — tiny serial add)
    int wbase = 0;
    #pragma unroll
    for (int i = 0; i < WAVES; ++i)
        wbase += (i < wv) ? wsum[i] : 0;

    const int excl = wbase + ws - run; // exclusive prefix for this thread

    // ---- publish cs row to LDS (swizzled) ----
    #pragma unroll
    for (int i = 0; i < PER_THREAD; ++i)
        cs[swz(tid * PER_THREAD + i)] = excl + loc[i];
    __syncthreads();

    // ---- windowed difference + masked writeback ----
    const int   m    = mask_size[s];             // uniform per block
    const float mval = (float)(*mask_value_p);

    const float4* x4  = reinterpret_cast<const float4*>(x + base);
    float4*       o4  = reinterpret_cast<float4*>(out + base);
    float4*       mo4 = reinterpret_cast<float4*>(mask_out + base);

    #pragma unroll
    for (int j = 0; j < 4; ++j) {
        float4 xv = x4[tid * 4 + j];
        float4 ov, mo;
        #pragma unroll
        for (int k = 0; k < 4; ++k) {
            int t = tid * PER_THREAD + j * 4 + k;
            int c = excl + loc[j * 4 + k];       // own cs from registers
            int pidx = t - m - 1;
            int p = (pidx >= 0) ? cs[swz(pidx)] : 0;
            bool msk = (c - p) >= 1;
            (&ov.x)[k] = msk ? mval : (&xv.x)[k];
            (&mo.x)[k] = msk ? 1.0f : 0.0f;
        }
        o4[tid * 4 + j] = ov;
        if (write_mask) mo4[tid * 4 + j] = mo;
    }
}

extern "C" void kernel_launch(void* const* d_in, const int* in_sizes, int n_in,
                              void* d_out, int out_size, void* d_ws, size_t ws_size,
                              hipStream_t stream) {
    const float* x          = (const float*)d_in[0];
    const int*   idx_mask   = (const int*)d_in[1];
    const int*   mask_size  = (const int*)d_in[2];
    const int*   mask_value = (const int*)d_in[3];

    const int n    = in_sizes[0];               // B*S*T = 33554432
    const int rows = n / TDIM;                  // B*S = 8192
    float* out = (float*)d_out;
    const int write_mask = (out_size >= 2 * n) ? 1 : 0;
    float* mask_out = out + n;                  // second tuple output, flat-concat

    segmask_kernel<<<rows, THREADS, 0, stream>>>(
        x, idx_mask, mask_size, mask_value, out, mask_out, write_mask);
}

// Round 6
// 434.090 us; speedup vs baseline: 1.2682x; 1.2682x over previous
//
#include <hip/hip_runtime.h>
#include <stdint.h>

// RandomSegmentMask: B=64, S=128, T=4096
// mask[b,s,t] = exists start in [t - m_s, t];  out = mask ? mask_value : x
//
// R5 post-mortem: WRITE_SIZE was 694 MB vs 268 ideal (2.6x amplification) --
// per-thread-contiguous float4 stores gave each wave-store a stride-64B
// scatter (1KB data spread over 4KB), causing partial-line HBM writes.
// R6 fix: phase 2 re-mapped so each wave-store is fully contiguous
// (lane i writes byte i*16 of a 4KB block). c is re-read from swizzled LDS
// (2-way bank access = free) instead of registers.

#define TDIM 4096
#define SDIM 128
#define THREADS 256
#define PER_THREAD (TDIM / THREADS) // 16
#define WAVES (THREADS / 64)        // 4

// word-index swizzle: XOR low-5 bits with bits 5..9. Bijective involution
// within a 4096-word row.
__device__ __forceinline__ int swz(int a) { return a ^ ((a >> 5) & 31); }

__global__ __launch_bounds__(THREADS)
void segmask_kernel(const float* __restrict__ x,
                    const int* __restrict__ idx_mask,
                    const int* __restrict__ mask_size,
                    const int* __restrict__ mask_value_p,
                    float* __restrict__ out,
                    float* __restrict__ mask_out,
                    int write_mask)
{
    __shared__ int cs[TDIM];        // 16 KB, swizzled word index
    __shared__ int wsum[WAVES];     // per-wave totals

    const int row  = blockIdx.x;                // b*S + s
    const int s    = row & (SDIM - 1);
    const int tid  = threadIdx.x;
    const int lane = tid & 63;
    const int wv   = tid >> 6;
    const long long base = (long long)row * TDIM;

    // ---- phase 1: load 16 int32 bools, local cumsum (owner: 16 contiguous) ----
    const int4* im4 = reinterpret_cast<const int4*>(idx_mask + base);
    int loc[PER_THREAD];
    int run = 0;
    #pragma unroll
    for (int j = 0; j < 4; ++j) {
        int4 v = im4[tid * 4 + j];
        run += (v.x != 0); loc[j * 4 + 0] = run;
        run += (v.y != 0); loc[j * 4 + 1] = run;
        run += (v.z != 0); loc[j * 4 + 2] = run;
        run += (v.w != 0); loc[j * 4 + 3] = run;
    }

    // wave-level inclusive scan of per-thread sums
    int ws = run;
    #pragma unroll
    for (int off = 1; off < 64; off <<= 1) {
        int up = __shfl_up(ws, off, 64);
        if (lane >= off) ws += up;
    }
    if (lane == 63) wsum[wv] = ws;
    __syncthreads();

    int wbase = 0;
    #pragma unroll
    for (int i = 0; i < WAVES; ++i)
        wbase += (i < wv) ? wsum[i] : 0;

    const int excl = wbase + ws - run;

    // publish cs row to LDS (swizzled; 2-way bank access = free)
    #pragma unroll
    for (int i = 0; i < PER_THREAD; ++i)
        cs[swz(tid * PER_THREAD + i)] = excl + loc[i];
    __syncthreads();

    // ---- phase 2: wave-contiguous loads/stores ----
    // thread handles float4 group g = j*256 + tid  -> lane i's 16B at byte i*16
    // of a contiguous 4KB block per store instruction.
    const int   m    = mask_size[s];             // uniform per block
    const float mval = (float)(*mask_value_p);

    const float4* x4  = reinterpret_cast<const float4*>(x + base);
    float4*       o4  = reinterpret_cast<float4*>(out + base);
    float4*       mo4 = reinterpret_cast<float4*>(mask_out + base);

    #pragma unroll
    for (int j = 0; j < 4; ++j) {
        const int g  = j * THREADS + tid;        // float4 index within row
        const int t0 = g * 4;
        float4 xv = x4[g];
        float4 ov, mo;
        #pragma unroll
        for (int k = 0; k < 4; ++k) {
            int t = t0 + k;
            int c = cs[swz(t)];
            int pidx = t - m - 1;
            int p = (pidx >= 0) ? cs[swz(pidx)] : 0;
            bool msk = (c - p) >= 1;
            (&ov.x)[k] = msk ? mval : (&xv.x)[k];
            (&mo.x)[k] = msk ? 1.0f : 0.0f;
        }
        o4[g] = ov;
        if (write_mask) mo4[g] = mo;
    }
}

extern "C" void kernel_launch(void* const* d_in, const int* in_sizes, int n_in,
                              void* d_out, int out_size, void* d_ws, size_t ws_size,
                              hipStream_t stream) {
    const float* x          = (const float*)d_in[0];
    const int*   idx_mask   = (const int*)d_in[1];
    const int*   mask_size  = (const int*)d_in[2];
    const int*   mask_value = (const int*)d_in[3];

    const int n    = in_sizes[0];               // B*S*T = 33554432
    const int rows = n / TDIM;                  // B*S = 8192
    float* out = (float*)d_out;
    const int write_mask = (out_size >= 2 * n) ? 1 : 0;
    float* mask_out = out + n;                  // second tuple output, flat-concat

    segmask_kernel<<<rows, THREADS, 0, stream>>>(
        x, idx_mask, mask_size, mask_value, out, mask_out, write_mask);
}

// Round 7
// 433.274 us; speedup vs baseline: 1.2706x; 1.0019x over previous
//
#include <hip/hip_runtime.h>
#include <stdint.h>

// RandomSegmentMask: B=64, S=128, T=4096
// mask[b,s,t] = exists start in [t - m_s, t];  out = mask ? mask_value : x
//
// R6 post-mortem: store fix confirmed (segmask 255 -> ~139us, out of top-5).
// R7: phase-1 loads were still stride-64B scatters per wave instruction
// (4x L2-line transactions). Now ALL global ops are wave-contiguous:
// thread owns chunks g = j*256+tid (4 elems each); chunk sums scanned via
// two-level LDS scan; c values carried in registers from phase 1 to phase 2
// (same mapping), only the windowed p-read hits LDS (swizzled, 2-way=free).

#define TDIM 4096
#define SDIM 128
#define THREADS 256
#define WAVES (THREADS / 64)        // 4

// word-index swizzle: XOR low-5 bits with bits 5..9. Bijective involution
// within a 4096-word row; keeps the stride-4 window reads at 2-way (free).
__device__ __forceinline__ int swz(int a) { return a ^ ((a >> 5) & 31); }

__global__ __launch_bounds__(THREADS)
void segmask_kernel(const float* __restrict__ x,
                    const int* __restrict__ idx_mask,
                    const int* __restrict__ mask_size,
                    const int* __restrict__ mask_value_p,
                    float* __restrict__ out,
                    float* __restrict__ mask_out,
                    int write_mask)
{
    __shared__ int cs[TDIM];           // 16 KB swizzled cumsum row
    __shared__ int chs[TDIM / 4];      // 4 KB chunk sums -> chunk excl prefixes
    __shared__ int wsum[WAVES];

    const int row  = blockIdx.x;                // b*S + s
    const int s    = row & (SDIM - 1);
    const int tid  = threadIdx.x;
    const int lane = tid & 63;
    const int wv   = tid >> 6;
    const long long base = (long long)row * TDIM;

    // ---- 1a: wave-contiguous idx_mask loads; per-chunk bits + sums ----
    const int4* im4 = reinterpret_cast<const int4*>(idx_mask + base);
    int b[4][4];
    #pragma unroll
    for (int j = 0; j < 4; ++j) {
        const int g = j * THREADS + tid;        // chunk index (4 elems/chunk)
        int4 v = im4[g];                        // lane i: 16B at byte i*16 ✓
        b[j][0] = (v.x != 0); b[j][1] = (v.y != 0);
        b[j][2] = (v.z != 0); b[j][3] = (v.w != 0);
        chs[g] = b[j][0] + b[j][1] + b[j][2] + b[j][3];
    }
    __syncthreads();

    // ---- 1b: scan of 1024 chunk sums ----
    // thread scans 4 CONTIGUOUS chunks [tid*4, tid*4+4) via one b128 read
    int4 cv = reinterpret_cast<const int4*>(chs)[tid];
    const int l0 = cv.x, l1 = l0 + cv.y, l2 = l1 + cv.z, l3 = l2 + cv.w;
    int ws = l3;
    #pragma unroll
    for (int off = 1; off < 64; off <<= 1) {
        int up = __shfl_up(ws, off, 64);
        if (lane >= off) ws += up;
    }
    if (lane == 63) wsum[wv] = ws;
    __syncthreads();                            // also fences cv reads pre-overwrite
    int wbase = 0;
    #pragma unroll
    for (int i = 0; i < WAVES; ++i) wbase += (i < wv) ? wsum[i] : 0;
    const int excl = wbase + ws - l3;           // excl prefix before chunk tid*4
    int4 pv; pv.x = excl; pv.y = excl + l0; pv.z = excl + l1; pv.w = excl + l2;
    reinterpret_cast<int4*>(chs)[tid] = pv;     // in-place chunk excl prefixes
    __syncthreads();

    // ---- 1c: cs values for owned chunks -> registers + swizzled LDS ----
    int c[4][4];
    #pragma unroll
    for (int j = 0; j < 4; ++j) {
        const int g  = j * THREADS + tid;
        const int cp = chs[g];                  // lanes stride-1: conflict-free
        const int t0 = g * 4;
        c[j][0] = cp      + b[j][0];
        c[j][1] = c[j][0] + b[j][1];
        c[j][2] = c[j][1] + b[j][2];
        c[j][3] = c[j][2] + b[j][3];
        cs[swz(t0 + 0)] = c[j][0];
        cs[swz(t0 + 1)] = c[j][1];
        cs[swz(t0 + 2)] = c[j][2];
        cs[swz(t0 + 3)] = c[j][3];
    }
    __syncthreads();

    // ---- 2: wave-contiguous streaming; c from registers, p from LDS ----
    const int   m    = mask_size[s];            // uniform per block
    const float mval = (float)(*mask_value_p);

    const float4* x4  = reinterpret_cast<const float4*>(x + base);
    float4*       o4  = reinterpret_cast<float4*>(out + base);
    float4*       mo4 = reinterpret_cast<float4*>(mask_out + base);

    #pragma unroll
    for (int j = 0; j < 4; ++j) {
        const int g  = j * THREADS + tid;
        const int t0 = g * 4;
        float4 xv = x4[g];
        float4 ov, mo;
        #pragma unroll
        for (int k = 0; k < 4; ++k) {
            const int t = t0 + k;
            const int pidx = t - m - 1;
            const int p = (pidx >= 0) ? cs[swz(pidx)] : 0;
            const bool msk = (c[j][k] - p) >= 1;
            (&ov.x)[k] = msk ? mval : (&xv.x)[k];
            (&mo.x)[k] = msk ? 1.0f : 0.0f;
        }
        o4[g] = ov;
        if (write_mask) mo4[g] = mo;
    }
}

extern "C" void kernel_launch(void* const* d_in, const int* in_sizes, int n_in,
                              void* d_out, int out_size, void* d_ws, size_t ws_size,
                              hipStream_t stream) {
    const float* x          = (const float*)d_in[0];
    const int*   idx_mask   = (const int*)d_in[1];
    const int*   mask_size  = (const int*)d_in[2];
    const int*   mask_value = (const int*)d_in[3];

    const int n    = in_sizes[0];               // B*S*T = 33554432
    const int rows = n / TDIM;                  // B*S = 8192
    float* out = (float*)d_out;
    const int write_mask = (out_size >= 2 * n) ? 1 : 0;
    float* mask_out = out + n;                  // second tuple output, flat-concat

    segmask_kernel<<<rows, THREADS, 0, stream>>>(
        x, idx_mask, mask_size, mask_value, out, mask_out, write_mask);
}